// Round 1
// baseline (845.108 us; speedup 1.0000x reference)
//
#include <hip/hip_runtime.h>
#include <hip/hip_bf16.h>

#define L_SEQ 2048
#define DM 1024
#define DI 2048
#define DS 128
#define NH 32
#define HD 64
#define DPROJ 4384
#define DPAD 4480
#define NBATCH 2

typedef unsigned short u16;
typedef __attribute__((ext_vector_type(8))) short short8;
typedef __attribute__((ext_vector_type(4))) float f32x4;

__device__ __forceinline__ u16 f2bf(float f) {
  union { float f; unsigned u; } c; c.f = f;
  unsigned u = c.u;
  u += 0x7fffu + ((u >> 16) & 1u);
  return (u16)(u >> 16);
}

__device__ __forceinline__ float siluf(float x) {
  return x / (1.0f + expf(-x));
}

// ---------------- RMSNorm (f32 in -> bf16 out) ----------------
__global__ __launch_bounds__(256) void rmsnorm_kernel(
    const float* __restrict__ x, const float* __restrict__ w,
    u16* __restrict__ xnb) {
  int m = blockIdx.x;
  int t = threadIdx.x;
  const float* row = x + (size_t)m * DM;
  float4 v = *(const float4*)(row + t * 4);
  float ss = v.x * v.x + v.y * v.y + v.z * v.z + v.w * v.w;
#pragma unroll
  for (int o = 32; o > 0; o >>= 1) ss += __shfl_xor(ss, o);
  __shared__ float sred[4];
  if ((t & 63) == 0) sred[t >> 6] = ss;
  __syncthreads();
  ss = sred[0] + sred[1] + sred[2] + sred[3];
  float rs = rsqrtf(ss * (1.0f / DM) + 1e-6f);
  float4 wv = *(const float4*)(w + t * 4);
  ushort4 o;
  o.x = f2bf(v.x * rs * wv.x);
  o.y = f2bf(v.y * rs * wv.y);
  o.z = f2bf(v.z * rs * wv.z);
  o.w = f2bf(v.w * rs * wv.w);
  *(ushort4*)(xnb + (size_t)m * DM + t * 4) = o;
}

// ---------------- weight conversions ----------------
__global__ __launch_bounds__(256) void cvt_w1_kernel(
    const float* __restrict__ w, u16* __restrict__ o) {
  int r = blockIdx.x;          // 0..4479 (padded rows)
  int c = threadIdx.x * 4;
  ushort4 u;
  if (r < DPROJ) {
    float4 v = *(const float4*)(w + (size_t)r * DM + c);
    u.x = f2bf(v.x); u.y = f2bf(v.y); u.z = f2bf(v.z); u.w = f2bf(v.w);
  } else {
    u.x = 0; u.y = 0; u.z = 0; u.w = 0;
  }
  *(ushort4*)(o + (size_t)r * DM + c) = u;
}

__global__ __launch_bounds__(256) void cvt_w2_kernel(
    const float* __restrict__ w, u16* __restrict__ o) {
  size_t i = ((size_t)blockIdx.x * 256 + threadIdx.x) * 8;
  float4 v0 = *(const float4*)(w + i);
  float4 v1 = *(const float4*)(w + i + 4);
  ushort4 a, b;
  a.x = f2bf(v0.x); a.y = f2bf(v0.y); a.z = f2bf(v0.z); a.w = f2bf(v0.w);
  b.x = f2bf(v1.x); b.y = f2bf(v1.y); b.z = f2bf(v1.z); b.w = f2bf(v1.w);
  *(ushort4*)(o + i) = a;
  *(ushort4*)(o + i + 4) = b;
}

// ---------------- bf16 MFMA GEMM: C[m,n] = sum_k A[m,k]*B[n,k] (+resid) ----
// A: M x K bf16 row-major, Bw: N x K bf16 row-major, C: M x N f32 row-major.
__global__ __launch_bounds__(256, 2) void gemm_bt(
    const u16* __restrict__ A, const u16* __restrict__ Bw,
    float* __restrict__ C, const float* __restrict__ resid,
    int M, int N, int K) {
  __shared__ u16 lA[128 * 32];
  __shared__ u16 lB[128 * 32];
  const int tid = threadIdx.x;
  const int wv = tid >> 6, lane = tid & 63;
  const int wm = wv >> 1, wn = wv & 1;
  const int m0 = blockIdx.y * 128, n0 = blockIdx.x * 128;

  // staging: thread tid covers 16B at LDS byte tid*16 (+4096 for round 1)
  const int rowS = tid >> 2;              // 0..63
  const int colS = (tid & 3) * 8;         // ushort offset within 32-k row
  const u16* gA0 = A + (size_t)(m0 + rowS) * K + colS;
  const u16* gA1 = A + (size_t)(m0 + rowS + 64) * K + colS;
  const u16* gB0 = Bw + (size_t)(n0 + rowS) * K + colS;
  const u16* gB1 = Bw + (size_t)(n0 + rowS + 64) * K + colS;

  f32x4 acc[4][4] = {};
  short8 ra0 = *(const short8*)gA0;
  short8 ra1 = *(const short8*)gA1;
  short8 rb0 = *(const short8*)gB0;
  short8 rb1 = *(const short8*)gB1;

  const int nk = K >> 5;
  for (int kt = 0; kt < nk; ++kt) {
    __syncthreads();
    *(short8*)&lA[tid * 8] = ra0;
    *(short8*)&lA[2048 + tid * 8] = ra1;
    *(short8*)&lB[tid * 8] = rb0;
    *(short8*)&lB[2048 + tid * 8] = rb1;
    __syncthreads();
    if (kt + 1 < nk) {
      int ko = (kt + 1) << 5;
      ra0 = *(const short8*)(gA0 + ko);
      ra1 = *(const short8*)(gA1 + ko);
      rb0 = *(const short8*)(gB0 + ko);
      rb1 = *(const short8*)(gB1 + ko);
    }
    short8 af[4], bfr[4];
    const int r = lane & 15;
    const int koff = (lane >> 4) * 8;
#pragma unroll
    for (int i = 0; i < 4; ++i)
      af[i] = *(const short8*)&lA[(wm * 64 + i * 16 + r) * 32 + koff];
#pragma unroll
    for (int j = 0; j < 4; ++j)
      bfr[j] = *(const short8*)&lB[(wn * 64 + j * 16 + r) * 32 + koff];
#pragma unroll
    for (int i = 0; i < 4; ++i)
#pragma unroll
      for (int j = 0; j < 4; ++j)
        acc[i][j] = __builtin_amdgcn_mfma_f32_16x16x32_bf16(
            af[i], bfr[j], acc[i][j], 0, 0, 0);
  }

  const int rbase = m0 + wm * 64 + (lane >> 4) * 4;
  const int cbase = n0 + wn * 64 + (lane & 15);
#pragma unroll
  for (int i = 0; i < 4; ++i) {
#pragma unroll
    for (int j = 0; j < 4; ++j) {
      int row0 = rbase + i * 16;
      int col = cbase + j * 16;
#pragma unroll
      for (int rr = 0; rr < 4; ++rr) {
        size_t o = (size_t)(row0 + rr) * N + col;
        float v = acc[i][j][rr];
        if (resid) v += resid[o];
        C[o] = v;
      }
    }
  }
}

// ---------------- depthwise causal conv (K=4) + SiLU ----------------
__global__ __launch_bounds__(256) void conv_kernel(
    const float* __restrict__ proj, const float* __restrict__ cw,
    const float* __restrict__ cb, float* __restrict__ xh) {
  int m = blockIdx.x;            // b*L + l
  int l = m & (L_SEQ - 1);
  int c0 = threadIdx.x * 8;
  float4 wv[8];
#pragma unroll
  for (int j = 0; j < 8; ++j) wv[j] = *(const float4*)(cw + (size_t)(c0 + j) * 4);
  float acc[8];
#pragma unroll
  for (int j = 0; j < 8; ++j) acc[j] = cb[c0 + j];
#pragma unroll
  for (int k = 0; k < 4; ++k) {
    int lk = l + k - 3;
    if (lk >= 0) {
      const float* row = proj + (size_t)(m + k - 3) * DPAD + DI + c0;
      float4 r0 = *(const float4*)row;
      float4 r1 = *(const float4*)(row + 4);
      float rv[8] = {r0.x, r0.y, r0.z, r0.w, r1.x, r1.y, r1.z, r1.w};
#pragma unroll
      for (int j = 0; j < 8; ++j) {
        float wk = (k == 0) ? wv[j].x : (k == 1) ? wv[j].y : (k == 2) ? wv[j].z : wv[j].w;
        acc[j] = fmaf(rv[j], wk, acc[j]);
      }
    }
  }
  float4 o0, o1;
  o0.x = siluf(acc[0]); o0.y = siluf(acc[1]); o0.z = siluf(acc[2]); o0.w = siluf(acc[3]);
  o1.x = siluf(acc[4]); o1.y = siluf(acc[5]); o1.z = siluf(acc[6]); o1.w = siluf(acc[7]);
  float* out = xh + (size_t)m * DI + c0;
  *(float4*)out = o0;
  *(float4*)(out + 4) = o1;
}

// ---------------- dt / dA ----------------
__global__ __launch_bounds__(256) void dtda_kernel(
    const float* __restrict__ proj, const float* __restrict__ dt_bias,
    const float* __restrict__ A_log, float* __restrict__ dAdt) {
  int idx = blockIdx.x * 256 + threadIdx.x;   // m*32 + h
  int m = idx >> 5, h = idx & 31;
  float raw = proj[(size_t)m * DPAD + (2 * DI + 2 * DS) + h] + dt_bias[h];
  float dt = fmaxf(raw, 0.0f) + log1pf(expf(-fabsf(raw)));
  float dA = expf(-expf(A_log[h]) * dt);
  float2 o; o.x = dA; o.y = dt;
  *(float2*)(dAdt + (size_t)idx * 2) = o;
}

// ---------------- selective scan ----------------
// 1024 waves: wid = b*512 + h*16 + pw. lane = pg*16 + ng.
// Each lane: p = pw*4+pg (one row of state), n-slice = ng*8..ng*8+8.
// y (incl. D*xh) overwrites xh in place.
#define SCAN_BODY(T, PB0, PB1, PC0, PC1, PXV, PAD)                            \
  {                                                                           \
    int tn = (T) + 2; if (tn > L_SEQ - 1) tn = L_SEQ - 1;                     \
    size_t ro = (size_t)tn * DPAD;                                            \
    float4 fB0 = PB0, fB1 = PB1, fC0 = PC0, fC1 = PC1;                        \
    float fxv = PXV; float2 fad = PAD;                                        \
    PB0 = *(const float4*)(Bb + ro); PB1 = *(const float4*)(Bb + ro + 4);     \
    PC0 = *(const float4*)(Cb + ro); PC1 = *(const float4*)(Cb + ro + 4);     \
    PXV = xb[(size_t)tn * DI]; PAD = *(const float2*)(ab + (size_t)tn * 64);  \
    float dA = fad.x; float dtx = fad.y * fxv; float acc;                     \
    hs0 = fmaf(hs0, dA, dtx * fB0.x); acc = hs0 * fC0.x;                      \
    hs1 = fmaf(hs1, dA, dtx * fB0.y); acc = fmaf(hs1, fC0.y, acc);            \
    hs2 = fmaf(hs2, dA, dtx * fB0.z); acc = fmaf(hs2, fC0.z, acc);            \
    hs3 = fmaf(hs3, dA, dtx * fB0.w); acc = fmaf(hs3, fC0.w, acc);            \
    hs4 = fmaf(hs4, dA, dtx * fB1.x); acc = fmaf(hs4, fC1.x, acc);            \
    hs5 = fmaf(hs5, dA, dtx * fB1.y); acc = fmaf(hs5, fC1.y, acc);            \
    hs6 = fmaf(hs6, dA, dtx * fB1.z); acc = fmaf(hs6, fC1.z, acc);            \
    hs7 = fmaf(hs7, dA, dtx * fB1.w); acc = fmaf(hs7, fC1.w, acc);            \
    acc += __shfl_xor(acc, 1);                                                \
    acc += __shfl_xor(acc, 2);                                                \
    acc += __shfl_xor(acc, 4);                                                \
    acc += __shfl_xor(acc, 8);                                                \
    if (ng == pg)                                                             \
      xhy[((size_t)b * L_SEQ + (T)) * DI + h * HD + p] = fmaf(Dh, fxv, acc);  \
  }

__global__ __launch_bounds__(256) void scan_kernel(
    const float* __restrict__ proj, const float* __restrict__ dAdt,
    float* __restrict__ xhy, const float* __restrict__ Dv) {
  int wid = (blockIdx.x << 2) + (threadIdx.x >> 6);  // 0..1023
  int lane = threadIdx.x & 63;
  int ng = lane & 15, pg = lane >> 4;
  int pw = wid & 15;
  int h = (wid >> 4) & 31;
  int b = wid >> 9;
  int p = pw * 4 + pg;
  float Dh = Dv[h];
  const float* Bb = proj + (size_t)b * L_SEQ * DPAD + 2 * DI + ng * 8;
  const float* Cb = Bb + DS;
  const float* xb = xhy + (size_t)b * L_SEQ * DI + h * HD + p;
  const float* ab = dAdt + (size_t)b * L_SEQ * 64 + h * 2;

  float hs0 = 0, hs1 = 0, hs2 = 0, hs3 = 0, hs4 = 0, hs5 = 0, hs6 = 0, hs7 = 0;

  // prefetch t=0 (slot A) and t=1 (slot B)
  float4 aB0 = *(const float4*)(Bb);
  float4 aB1 = *(const float4*)(Bb + 4);
  float4 aC0 = *(const float4*)(Cb);
  float4 aC1 = *(const float4*)(Cb + 4);
  float axv = xb[0];
  float2 aad = *(const float2*)(ab);
  float4 bB0 = *(const float4*)(Bb + DPAD);
  float4 bB1 = *(const float4*)(Bb + DPAD + 4);
  float4 bC0 = *(const float4*)(Cb + DPAD);
  float4 bC1 = *(const float4*)(Cb + DPAD + 4);
  float bxv = xb[DI];
  float2 bad = *(const float2*)(ab + 64);

  for (int t = 0; t < L_SEQ; t += 2) {
    SCAN_BODY(t, aB0, aB1, aC0, aC1, axv, aad);
    SCAN_BODY(t + 1, bB0, bB1, bC0, bC1, bxv, bad);
  }
}

// ---------------- gating: yb = bf16(y * silu(z)) ----------------
__global__ __launch_bounds__(256) void gate_kernel(
    const float* __restrict__ xhy, const float* __restrict__ proj,
    u16* __restrict__ yb) {
  size_t i0 = ((size_t)blockIdx.x * 256 + threadIdx.x) * 8;
  size_t m = i0 >> 11;
  int c = (int)(i0 & 2047);
  float4 y0 = *(const float4*)(xhy + i0);
  float4 y1 = *(const float4*)(xhy + i0 + 4);
  const float* zp = proj + m * DPAD + c;
  float4 z0 = *(const float4*)zp;
  float4 z1 = *(const float4*)(zp + 4);
  ushort4 a, bq;
  a.x = f2bf(y0.x * siluf(z0.x));
  a.y = f2bf(y0.y * siluf(z0.y));
  a.z = f2bf(y0.z * siluf(z0.z));
  a.w = f2bf(y0.w * siluf(z0.w));
  bq.x = f2bf(y1.x * siluf(z1.x));
  bq.y = f2bf(y1.y * siluf(z1.y));
  bq.z = f2bf(y1.z * siluf(z1.z));
  bq.w = f2bf(y1.w * siluf(z1.w));
  *(ushort4*)(yb + i0) = a;
  *(ushort4*)(yb + i0 + 4) = bq;
}

extern "C" void kernel_launch(void* const* d_in, const int* in_sizes, int n_in,
                              void* d_out, int out_size, void* d_ws, size_t ws_size,
                              hipStream_t stream) {
  const float* x      = (const float*)d_in[0];
  const float* norm_w = (const float*)d_in[1];
  const float* w1     = (const float*)d_in[2];
  const float* cw     = (const float*)d_in[3];
  const float* cb     = (const float*)d_in[4];
  const float* A_log  = (const float*)d_in[5];
  const float* Dv     = (const float*)d_in[6];
  const float* dt_b   = (const float*)d_in[7];
  const float* w2     = (const float*)d_in[8];
  float* out = (float*)d_out;

  char* ws = (char*)d_ws;
  u16*   xnb  = (u16*)(ws);                    // 4096*1024*2      = 8,388,608
  u16*   w1b  = (u16*)(ws + 8388608);          // 4480*1024*2      = 9,175,040
  u16*   w2b  = (u16*)(ws + 17563648);         // 1024*2048*2      = 4,194,304
  float* proj = (float*)(ws + 21757952);       // 4096*4480*4      = 73,400,320
  float* xhy  = (float*)(ws + 95158272);       // 4096*2048*4      = 33,554,432
  float* dAdt = (float*)(ws + 128712704);      // 4096*32*2*4      = 1,048,576
  u16*   yb   = (u16*)(ws + 129761280);        // 4096*2048*2      = 16,777,216

  const int M = NBATCH * L_SEQ;  // 4096

  rmsnorm_kernel<<<M, 256, 0, stream>>>(x, norm_w, xnb);
  cvt_w1_kernel<<<DPAD, 256, 0, stream>>>(w1, w1b);
  cvt_w2_kernel<<<1024, 256, 0, stream>>>(w2, w2b);
  gemm_bt<<<dim3(DPAD / 128, M / 128), 256, 0, stream>>>(
      xnb, w1b, proj, nullptr, M, DPAD, DM);
  conv_kernel<<<M, 256, 0, stream>>>(proj, cw, cb, xhy);
  dtda_kernel<<<M * NH / 256, 256, 0, stream>>>(proj, dt_b, A_log, dAdt);
  scan_kernel<<<256, 256, 0, stream>>>(proj, dAdt, xhy, Dv);
  gate_kernel<<<M * DI / 2048, 256, 0, stream>>>(xhy, proj, yb);
  gemm_bt<<<dim3(DM / 128, M / 128), 256, 0, stream>>>(
      yb, w2b, out, x, M, DM, DI);
}